// Round 1
// baseline (459.466 us; speedup 1.0000x reference)
//
#include <hip/hip_runtime.h>
#include <math.h>

#define BSZ   4096
#define F     26
#define VOC   100000
#define D     64
#define AD    64
#define ND    13
#define FEA   77
#define NPAIR 325
#define H1    256
#define H2    128
#define H3    64
#define EPSF  1e-5f

// ---------------- K1: attention (one block per batch row) ----------------
__global__ __launch_bounds__(512) void k_attn(
    const int* __restrict__ sx, const float* __restrict__ dx,
    const float* __restrict__ emb, const float* __restrict__ attW,
    const float* __restrict__ attb, const float* __restrict__ attdW,
    const float* __restrict__ attdb, float* __restrict__ x)
{
  __shared__ float e[F][D];                 // 6.5 KB
  __shared__ float bi[NPAIR][D];            // 83.2 KB
  __shared__ float sc[NPAIR];               // scores -> softmax weights
  __shared__ unsigned char p1t[NPAIR], p2t[NPAIR];
  __shared__ float red[8];
  __shared__ float part[8][D];
  __shared__ float bcast[2];

  const int b    = blockIdx.x;
  const int t    = threadIdx.x;
  const int lane = t & 63;
  const int wv   = t >> 6;                  // 0..7

  // pair index tables (triu k=1, row-major)
  for (int p = t; p < NPAIR; p += 512) {
    int i = 0, rem = p;
    while (rem >= F - 1 - i) { rem -= F - 1 - i; ++i; }
    p1t[p] = (unsigned char)i;
    p2t[p] = (unsigned char)(i + 1 + rem);
  }

  // gather embeddings for this row: e[f][d] = emb[f, sx[b,f], d]
  for (int k = t; k < F * D; k += 512) {
    int f = k >> 6, d = k & 63;
    int row = sx[b * F + f];
    e[f][d] = emb[((size_t)f * VOC + row) * D + d];
  }

  // W column j=lane into registers (same for every wave)
  float Wc[D];
  #pragma unroll
  for (int d = 0; d < D; ++d) Wc[d] = attW[d * AD + lane];
  const float bj  = attb[lane];
  const float dWj = attdW[lane];
  const float db0 = attdb[0];

  __syncthreads();

  // bi[p][d] = e[i1][d] * e[i2][d]
  for (int k = t; k < NPAIR * D; k += 512) {
    int p = k >> 6, d = k & 63;
    bi[p][d] = e[p1t[p]][d] * e[p2t[p]][d];
  }
  __syncthreads();

  // scores: each wave takes 2 pairs per sweep; lane j computes a_j
  for (int base = wv * 2; base < NPAIR; base += 16) {
    const int p0 = base, p1 = base + 1;
    const bool v1 = (p1 < NPAIR);
    float acc0 = bj, acc1 = bj;
    const float4* r0 = (const float4*)bi[p0];
    const float4* r1 = (const float4*)bi[v1 ? p1 : p0];
    #pragma unroll
    for (int d4 = 0; d4 < D / 4; ++d4) {
      float4 q0 = r0[d4];
      float4 q1 = r1[d4];
      acc0 = fmaf(q0.x, Wc[4*d4+0], acc0);
      acc0 = fmaf(q0.y, Wc[4*d4+1], acc0);
      acc0 = fmaf(q0.z, Wc[4*d4+2], acc0);
      acc0 = fmaf(q0.w, Wc[4*d4+3], acc0);
      acc1 = fmaf(q1.x, Wc[4*d4+0], acc1);
      acc1 = fmaf(q1.y, Wc[4*d4+1], acc1);
      acc1 = fmaf(q1.z, Wc[4*d4+2], acc1);
      acc1 = fmaf(q1.w, Wc[4*d4+3], acc1);
    }
    float s0 = fmaxf(acc0, 0.f) * dWj;
    float s1 = fmaxf(acc1, 0.f) * dWj;
    #pragma unroll
    for (int off = 32; off; off >>= 1) {
      s0 += __shfl_xor(s0, off);
      s1 += __shfl_xor(s1, off);
    }
    if (lane == 0) sc[p0] = s0 + db0;
    if (lane == 1 && v1) sc[p1] = s1 + db0;
  }
  __syncthreads();

  // softmax over 325 scores
  float m = -1e30f;
  for (int p = t; p < NPAIR; p += 512) m = fmaxf(m, sc[p]);
  #pragma unroll
  for (int off = 32; off; off >>= 1) m = fmaxf(m, __shfl_xor(m, off));
  if (lane == 0) red[wv] = m;
  __syncthreads();
  if (t == 0) {
    float mm = red[0];
    #pragma unroll
    for (int i = 1; i < 8; ++i) mm = fmaxf(mm, red[i]);
    bcast[0] = mm;
  }
  __syncthreads();
  m = bcast[0];
  float s = 0.f;
  for (int p = t; p < NPAIR; p += 512) {
    float w = expf(sc[p] - m);
    sc[p] = w;
    s += w;
  }
  #pragma unroll
  for (int off = 32; off; off >>= 1) s += __shfl_xor(s, off);
  if (lane == 0) red[wv] = s;
  __syncthreads();
  if (t == 0) {
    float ss = 0.f;
    #pragma unroll
    for (int i = 0; i < 8; ++i) ss += red[i];
    bcast[1] = ss;
  }
  __syncthreads();
  const float invZ = 1.f / bcast[1];
  for (int p = t; p < NPAIR; p += 512) sc[p] *= invZ;
  __syncthreads();

  // att_out[d] = sum_p w_p * bi[p][d]
  {
    float acc = 0.f;
    const int d = lane;
    for (int p = wv; p < NPAIR; p += 8) acc += sc[p] * bi[p][d];
    part[wv][d] = acc;
  }
  __syncthreads();
  if (t < D) {
    float ssum = 0.f;
    #pragma unroll
    for (int w = 0; w < 8; ++w) ssum += part[w][t];
    x[(size_t)b * FEA + t] = ssum;
  }
  if (t >= D && t < D + ND) {
    x[(size_t)b * FEA + t] = dx[b * ND + (t - D)];
  }
}

// ---------------- K2: batchnorm stats (block per feature) ----------------
__global__ __launch_bounds__(256) void k_bnstats(
    const float* __restrict__ x, const float* __restrict__ gamma,
    const float* __restrict__ beta, float* __restrict__ scale,
    float* __restrict__ shift)
{
  const int f = blockIdx.x;
  const int t = threadIdx.x;
  const int lane = t & 63;
  const int wv = t >> 6;
  double s = 0.0, s2 = 0.0;
  for (int b = t; b < BSZ; b += 256) {
    float v = x[(size_t)b * FEA + f];
    s += v;
    s2 += (double)v * v;
  }
  #pragma unroll
  for (int off = 32; off; off >>= 1) {
    s += __shfl_xor(s, off);
    s2 += __shfl_xor(s2, off);
  }
  __shared__ double rs[4], rs2[4];
  if (lane == 0) { rs[wv] = s; rs2[wv] = s2; }
  __syncthreads();
  if (t == 0) {
    double S = 0.0, S2 = 0.0;
    #pragma unroll
    for (int i = 0; i < 4; ++i) { S += rs[i]; S2 += rs2[i]; }
    double mu = S / BSZ;
    double var = S2 / BSZ - mu * mu;
    float g = gamma[f];
    float scl = (float)((double)g / sqrt(var + (double)EPSF));
    scale[f] = scl;
    shift[f] = beta[f] - (float)mu * scl;
  }
}

// ---------------- K3: MLP (16 rows per block) ----------------
__global__ __launch_bounds__(256) void k_mlp(
    const float* __restrict__ x,
    const float* __restrict__ scale, const float* __restrict__ shift,
    const float* __restrict__ w1, const float* __restrict__ b1,
    const float* __restrict__ w2, const float* __restrict__ b2,
    const float* __restrict__ w3, const float* __restrict__ b3,
    const float* __restrict__ wf, const float* __restrict__ bf,
    float* __restrict__ out)
{
  __shared__ float xn[16][80];
  __shared__ float h1s[16][H1];
  __shared__ float h2s[16][H2];
  __shared__ float h3s[16][H3];
  const int t = threadIdx.x;
  const int b0 = blockIdx.x * 16;

  for (int k = t; k < 16 * FEA; k += 256) {
    int r = k / FEA, f = k % FEA;
    xn[r][f] = x[(size_t)(b0 + r) * FEA + f] * scale[f] + shift[f];
  }
  __syncthreads();

  // layer 1: 77 -> 256 (thread = output j, 16 rows)
  {
    float acc[16];
    const float bb = b1[t];
    #pragma unroll
    for (int r = 0; r < 16; ++r) acc[r] = bb;
    for (int d = 0; d < FEA; ++d) {
      float wv = w1[d * H1 + t];
      #pragma unroll
      for (int r = 0; r < 16; ++r) acc[r] = fmaf(xn[r][d], wv, acc[r]);
    }
    #pragma unroll
    for (int r = 0; r < 16; ++r) h1s[r][t] = fmaxf(acc[r], 0.f);
  }
  __syncthreads();

  // layer 2: 256 -> 128 (j = t&127, 8 rows per half)
  {
    const int j = t & 127;
    const int rb = (t >> 7) * 8;
    float acc[8];
    const float bb = b2[j];
    #pragma unroll
    for (int r = 0; r < 8; ++r) acc[r] = bb;
    for (int k = 0; k < H1; ++k) {
      float wv = w2[k * H2 + j];
      #pragma unroll
      for (int r = 0; r < 8; ++r) acc[r] = fmaf(h1s[rb + r][k], wv, acc[r]);
    }
    #pragma unroll
    for (int r = 0; r < 8; ++r) h2s[rb + r][j] = fmaxf(acc[r], 0.f);
  }
  __syncthreads();

  // layer 3: 128 -> 64 (j = t&63, 4 rows per quarter)
  {
    const int j = t & 63;
    const int rb = (t >> 6) * 4;
    float acc[4];
    const float bb = b3[j];
    #pragma unroll
    for (int r = 0; r < 4; ++r) acc[r] = bb;
    for (int k = 0; k < H2; ++k) {
      float wv = w3[k * H3 + j];
      #pragma unroll
      for (int r = 0; r < 4; ++r) acc[r] = fmaf(h2s[rb + r][k], wv, acc[r]);
    }
    #pragma unroll
    for (int r = 0; r < 4; ++r) h3s[rb + r][j] = fmaxf(acc[r], 0.f);
  }
  __syncthreads();

  // final: 64 -> 1 + sigmoid
  if (t < 16) {
    float acc = bf[0];
    for (int k = 0; k < H3; ++k) acc = fmaf(h3s[t][k], wf[k], acc);
    out[b0 + t] = 1.f / (1.f + expf(-acc));
  }
}

extern "C" void kernel_launch(void* const* d_in, const int* in_sizes, int n_in,
                              void* d_out, int out_size, void* d_ws, size_t ws_size,
                              hipStream_t stream) {
  const int*   sx    = (const int*)  d_in[0];
  const float* dx    = (const float*)d_in[1];
  const float* emb   = (const float*)d_in[2];
  const float* attW  = (const float*)d_in[3];
  const float* attb  = (const float*)d_in[4];
  const float* attdW = (const float*)d_in[5];
  const float* attdb = (const float*)d_in[6];
  const float* gamma = (const float*)d_in[7];
  const float* beta  = (const float*)d_in[8];
  const float* w1    = (const float*)d_in[9];
  const float* b1    = (const float*)d_in[10];
  const float* w2    = (const float*)d_in[11];
  const float* b2    = (const float*)d_in[12];
  const float* w3    = (const float*)d_in[13];
  const float* b3    = (const float*)d_in[14];
  const float* wf    = (const float*)d_in[15];
  const float* bf    = (const float*)d_in[16];
  float* out = (float*)d_out;

  float* x     = (float*)d_ws;              // B*FEA
  float* scale = x + (size_t)BSZ * FEA;     // FEA
  float* shift = scale + FEA;               // FEA

  k_attn<<<BSZ, 512, 0, stream>>>(sx, dx, emb, attW, attb, attdW, attdb, x);
  k_bnstats<<<FEA, 256, 0, stream>>>(x, gamma, beta, scale, shift);
  k_mlp<<<BSZ / 16, 256, 0, stream>>>(x, scale, shift, w1, b1, w2, b2, w3, b3,
                                      wf, bf, out);
}

// Round 2
// 120.537 us; speedup vs baseline: 3.8118x; 3.8118x over previous
//
#include <hip/hip_runtime.h>
#include <math.h>

#define BSZ   4096
#define F     26
#define VOC   100000
#define D     64
#define AD    64
#define ND    13
#define FEA   77
#define NPAIR 325
#define NPAD  336    // 21 M-tiles of 16
#define MT    21
#define H1    256
#define H2    128
#define H3    64
#define EPSF  1e-5f

typedef __attribute__((ext_vector_type(8))) short short8;
typedef __attribute__((ext_vector_type(4))) float f32x4;

__device__ __forceinline__ unsigned short f2bf(float f) {
  unsigned int u = __float_as_uint(f);
  u += 0x7fffu + ((u >> 16) & 1u);   // RNE
  return (unsigned short)(u >> 16);
}
__device__ __forceinline__ float bf2f(short h) {
  return __uint_as_float(((unsigned int)(unsigned short)h) << 16);
}

// ---------------- K1: attention, MFMA score GEMM (one block per row) -------
__global__ __launch_bounds__(256) void k_attn(
    const int* __restrict__ sx, const float* __restrict__ dx,
    const float* __restrict__ emb, const float* __restrict__ attW,
    const float* __restrict__ attb, const float* __restrict__ attdW,
    const float* __restrict__ attdb, float* __restrict__ x)
{
  __shared__ unsigned short e_lds[F * D];        // bf16, 3.25 KB
  __shared__ unsigned short bi_lds[NPAD * D];    // bf16, 42 KB, XOR-swizzled
  __shared__ float sc[NPAD];
  __shared__ float wls[NPAD];
  __shared__ float part[4][D];
  __shared__ unsigned char p1t[NPAIR], p2t[NPAIR];
  __shared__ float red[4];
  __shared__ float bcast[2];

  const int b    = blockIdx.x;
  const int t    = threadIdx.x;
  const int lane = t & 63;
  const int wv   = t >> 6;                       // 0..3

  // pair tables
  for (int p = t; p < NPAIR; p += 256) {
    int i = 0, rem = p;
    while (rem >= F - 1 - i) { rem -= F - 1 - i; ++i; }
    p1t[p] = (unsigned char)i;
    p2t[p] = (unsigned char)(i + 1 + rem);
  }
  // zero the 11 pad rows of bi
  for (int k = t; k < (NPAD - NPAIR) * 8; k += 256) {
    int p = NPAIR + (k >> 3), g = k & 7;
    short8 z = {0,0,0,0,0,0,0,0};
    *(short8*)&bi_lds[p * D + g * 8] = z;
  }
  // gather embeddings -> bf16 LDS: e[f][d]
  for (int k = t; k < F * 16; k += 256) {        // 16 float4 per feature
    int f = k >> 4, q = k & 15;
    int row = sx[b * F + f];
    float4 v = *(const float4*)&emb[((size_t)f * VOC + row) * D + q * 4];
    unsigned short* dst = &e_lds[f * D + q * 4];
    dst[0] = f2bf(v.x); dst[1] = f2bf(v.y); dst[2] = f2bf(v.z); dst[3] = f2bf(v.w);
  }

  // B fragments (W columns) + biases, from global (L1-resident, 16 KB)
  short8 bfrag[2][4];
  float bj[4], dwj[4];
  {
    const int kb = (lane >> 4) * 8;
    const int cl = lane & 15;
    #pragma unroll
    for (int kk = 0; kk < 2; ++kk)
      #pragma unroll
      for (int n = 0; n < 4; ++n) {
        #pragma unroll
        for (int j = 0; j < 8; ++j) {
          int k = kk * 32 + kb + j;
          bfrag[kk][n][j] = (short)f2bf(attW[k * AD + n * 16 + cl]);
        }
      }
    #pragma unroll
    for (int n = 0; n < 4; ++n) {
      bj[n]  = attb[n * 16 + cl];
      dwj[n] = attdW[n * 16 + cl];
    }
  }
  const float db0 = attdb[0];
  __syncthreads();

  // bi[p][d] = e[i1][d]*e[i2][d] -> bf16, swizzled granule = g ^ (p&7)
  for (int k = t; k < NPAIR * 8; k += 256) {
    int p = k >> 3, g = k & 7;
    const short8 a = *(const short8*)&e_lds[p1t[p] * D + g * 8];
    const short8 bb = *(const short8*)&e_lds[p2t[p] * D + g * 8];
    short8 o;
    #pragma unroll
    for (int j = 0; j < 8; ++j)
      o[j] = (short)f2bf(bf2f(a[j]) * bf2f(bb[j]));
    *(short8*)&bi_lds[p * D + (g ^ (p & 7)) * 8] = o;
  }
  __syncthreads();

  // score GEMM: wave w owns M-tiles {w, w+4, ...}
  {
    const int row16 = lane & 15;
    const int kgrp  = lane >> 4;
    for (int m = wv; m < MT; m += 4) {
      const int row = m * 16 + row16;
      const int sw  = row & 7;
      const short8 a0 = *(const short8*)&bi_lds[row * D + (((0 * 4) + kgrp) ^ sw) * 8];
      const short8 a1 = *(const short8*)&bi_lds[row * D + (((1 * 4) + kgrp) ^ sw) * 8];
      f32x4 acc[4];
      #pragma unroll
      for (int n = 0; n < 4; ++n) {
        f32x4 z = {0.f, 0.f, 0.f, 0.f};
        acc[n] = __builtin_amdgcn_mfma_f32_16x16x32_bf16(a0, bfrag[0][n], z, 0, 0, 0);
        acc[n] = __builtin_amdgcn_mfma_f32_16x16x32_bf16(a1, bfrag[1][n], acc[n], 0, 0, 0);
      }
      // epilogue: s[pair] = sum_j relu(a+b)*dW ; pair = m*16 + kgrp*4 + r
      float v4[4];
      #pragma unroll
      for (int r = 0; r < 4; ++r) {
        float val = 0.f;
        #pragma unroll
        for (int n = 0; n < 4; ++n)
          val += fmaxf(acc[n][r] + bj[n], 0.f) * dwj[n];
        val += __shfl_xor(val, 1);
        val += __shfl_xor(val, 2);
        val += __shfl_xor(val, 4);
        val += __shfl_xor(val, 8);
        v4[r] = val + db0;
      }
      if (row16 == 0) {
        float4 o = {v4[0], v4[1], v4[2], v4[3]};
        *(float4*)&sc[m * 16 + kgrp * 4] = o;
      }
    }
  }
  __syncthreads();

  // softmax over 325 (pads masked)
  float mx = -1e30f;
  for (int p = t; p < NPAIR; p += 256) mx = fmaxf(mx, sc[p]);
  #pragma unroll
  for (int off = 32; off; off >>= 1) mx = fmaxf(mx, __shfl_xor(mx, off));
  if (lane == 0) red[wv] = mx;
  __syncthreads();
  if (t == 0) {
    float mm = fmaxf(fmaxf(red[0], red[1]), fmaxf(red[2], red[3]));
    bcast[0] = mm;
  }
  __syncthreads();
  mx = bcast[0];
  float s = 0.f;
  for (int p = t; p < NPAIR; p += 256) {
    float w = expf(sc[p] - mx);
    wls[p] = w;
    s += w;
  }
  if (t < NPAD - NPAIR) wls[NPAIR + t] = 0.f;
  #pragma unroll
  for (int off = 32; off; off >>= 1) s += __shfl_xor(s, off);
  if (lane == 0) red[wv] = s;
  __syncthreads();
  if (t == 0) bcast[1] = red[0] + red[1] + red[2] + red[3];
  __syncthreads();
  const float invZ = 1.f / bcast[1];
  for (int p = t; p < NPAIR; p += 256) wls[p] *= invZ;
  __syncthreads();

  // PV: att_out[d] = sum_p w[p]*bi[p][d]
  {
    const int dblk = lane & 7;                   // d = dblk*8..+8
    const int prow = wv * 8 + (lane >> 3);       // 0..31
    float acc[8] = {0,0,0,0,0,0,0,0};
    for (int p = prow; p < NPAD; p += 32) {
      const float wgt = wls[p];
      const short8 v = *(const short8*)&bi_lds[p * D + (dblk ^ (p & 7)) * 8];
      #pragma unroll
      for (int j = 0; j < 8; ++j)
        acc[j] = fmaf(wgt, bf2f(v[j]), acc[j]);
    }
    #pragma unroll
    for (int off = 8; off <= 32; off <<= 1)
      #pragma unroll
      for (int j = 0; j < 8; ++j)
        acc[j] += __shfl_xor(acc[j], off);
    if ((lane >> 3) == 0) {
      #pragma unroll
      for (int j = 0; j < 8; ++j)
        part[wv][dblk * 8 + j] = acc[j];
    }
  }
  __syncthreads();
  if (t < D) {
    float ssum = part[0][t] + part[1][t] + part[2][t] + part[3][t];
    x[(size_t)b * FEA + t] = ssum;
  }
  if (t >= D && t < FEA) {
    x[(size_t)b * FEA + t] = dx[b * ND + (t - D)];
  }
}

// ---------------- K2: batchnorm stats (block per feature) ----------------
__global__ __launch_bounds__(256) void k_bnstats(
    const float* __restrict__ x, const float* __restrict__ gamma,
    const float* __restrict__ beta, float* __restrict__ scale,
    float* __restrict__ shift)
{
  const int f = blockIdx.x;
  const int t = threadIdx.x;
  const int lane = t & 63;
  const int wv = t >> 6;
  double s = 0.0, s2 = 0.0;
  for (int b = t; b < BSZ; b += 256) {
    float v = x[(size_t)b * FEA + f];
    s += v;
    s2 += (double)v * v;
  }
  #pragma unroll
  for (int off = 32; off; off >>= 1) {
    s += __shfl_xor(s, off);
    s2 += __shfl_xor(s2, off);
  }
  __shared__ double rs[4], rs2[4];
  if (lane == 0) { rs[wv] = s; rs2[wv] = s2; }
  __syncthreads();
  if (t == 0) {
    double S = 0.0, S2 = 0.0;
    #pragma unroll
    for (int i = 0; i < 4; ++i) { S += rs[i]; S2 += rs2[i]; }
    double mu = S / BSZ;
    double var = S2 / BSZ - mu * mu;
    float g = gamma[f];
    float scl = (float)((double)g / sqrt(var + (double)EPSF));
    scale[f] = scl;
    shift[f] = beta[f] - (float)mu * scl;
  }
}

// ---------------- K3: MLP (16 rows per block) ----------------
__global__ __launch_bounds__(256) void k_mlp(
    const float* __restrict__ x,
    const float* __restrict__ scale, const float* __restrict__ shift,
    const float* __restrict__ w1, const float* __restrict__ b1,
    const float* __restrict__ w2, const float* __restrict__ b2,
    const float* __restrict__ w3, const float* __restrict__ b3,
    const float* __restrict__ wf, const float* __restrict__ bf,
    float* __restrict__ out)
{
  __shared__ float xn[16][80];
  __shared__ float h1s[16][H1];
  __shared__ float h2s[16][H2];
  __shared__ float h3s[16][H3];
  const int t = threadIdx.x;
  const int b0 = blockIdx.x * 16;

  for (int k = t; k < 16 * FEA; k += 256) {
    int r = k / FEA, f = k % FEA;
    xn[r][f] = x[(size_t)(b0 + r) * FEA + f] * scale[f] + shift[f];
  }
  __syncthreads();

  {
    float acc[16];
    const float bb = b1[t];
    #pragma unroll
    for (int r = 0; r < 16; ++r) acc[r] = bb;
    for (int d = 0; d < FEA; ++d) {
      float wv = w1[d * H1 + t];
      #pragma unroll
      for (int r = 0; r < 16; ++r) acc[r] = fmaf(xn[r][d], wv, acc[r]);
    }
    #pragma unroll
    for (int r = 0; r < 16; ++r) h1s[r][t] = fmaxf(acc[r], 0.f);
  }
  __syncthreads();

  {
    const int j = t & 127;
    const int rb = (t >> 7) * 8;
    float acc[8];
    const float bb = b2[j];
    #pragma unroll
    for (int r = 0; r < 8; ++r) acc[r] = bb;
    for (int k = 0; k < H1; ++k) {
      float wv = w2[k * H2 + j];
      #pragma unroll
      for (int r = 0; r < 8; ++r) acc[r] = fmaf(h1s[rb + r][k], wv, acc[r]);
    }
    #pragma unroll
    for (int r = 0; r < 8; ++r) h2s[rb + r][j] = fmaxf(acc[r], 0.f);
  }
  __syncthreads();

  {
    const int j = t & 63;
    const int rb = (t >> 6) * 4;
    float acc[4];
    const float bb = b3[j];
    #pragma unroll
    for (int r = 0; r < 4; ++r) acc[r] = bb;
    for (int k = 0; k < H2; ++k) {
      float wv = w3[k * H3 + j];
      #pragma unroll
      for (int r = 0; r < 4; ++r) acc[r] = fmaf(h2s[rb + r][k], wv, acc[r]);
    }
    #pragma unroll
    for (int r = 0; r < 4; ++r) h3s[rb + r][j] = fmaxf(acc[r], 0.f);
  }
  __syncthreads();

  if (t < 16) {
    float acc = bf[0];
    for (int k = 0; k < H3; ++k) acc = fmaf(h3s[t][k], wf[k], acc);
    out[b0 + t] = 1.f / (1.f + expf(-acc));
  }
}

extern "C" void kernel_launch(void* const* d_in, const int* in_sizes, int n_in,
                              void* d_out, int out_size, void* d_ws, size_t ws_size,
                              hipStream_t stream) {
  const int*   sx    = (const int*)  d_in[0];
  const float* dx    = (const float*)d_in[1];
  const float* emb   = (const float*)d_in[2];
  const float* attW  = (const float*)d_in[3];
  const float* attb  = (const float*)d_in[4];
  const float* attdW = (const float*)d_in[5];
  const float* attdb = (const float*)d_in[6];
  const float* gamma = (const float*)d_in[7];
  const float* beta  = (const float*)d_in[8];
  const float* w1    = (const float*)d_in[9];
  const float* b1    = (const float*)d_in[10];
  const float* w2    = (const float*)d_in[11];
  const float* b2    = (const float*)d_in[12];
  const float* w3    = (const float*)d_in[13];
  const float* b3    = (const float*)d_in[14];
  const float* wf    = (const float*)d_in[15];
  const float* bf    = (const float*)d_in[16];
  float* out = (float*)d_out;

  float* x     = (float*)d_ws;              // B*FEA
  float* scale = x + (size_t)BSZ * FEA;     // FEA
  float* shift = scale + FEA;               // FEA

  k_attn<<<BSZ, 256, 0, stream>>>(sx, dx, emb, attW, attb, attdW, attdb, x);
  k_bnstats<<<FEA, 256, 0, stream>>>(x, gamma, beta, scale, shift);
  k_mlp<<<BSZ / 16, 256, 0, stream>>>(x, scale, shift, w1, b1, w2, b2, w3, b3,
                                      wf, bf, out);
}

// Round 3
// 96.246 us; speedup vs baseline: 4.7739x; 1.2524x over previous
//
#include <hip/hip_runtime.h>
#include <hip/hip_bf16.h>
#include <math.h>

#define BSZ   4096
#define F     26
#define VOC   100000
#define D     64
#define AD    64
#define ND    13
#define FEA   77
#define NPAIR 325
#define NPAD  336    // 21 M-tiles of 16
#define MT    21
#define EP    68     // e row stride in floats (272B: bank advance 4/row -> 2-way max)
#define SCP   384    // per-wave score buffer size
#define H1    256
#define H2    128
#define H3    64
#define EPSF  1e-5f

typedef __attribute__((ext_vector_type(8))) short short8;
typedef __attribute__((ext_vector_type(4))) float f32x4;

union FragU { short8 s; unsigned int u[4]; };

__device__ __forceinline__ unsigned int pk2bf(float a, float b) {
  __hip_bfloat162 h = __float22bfloat162_rn(make_float2(a, b));  // v_cvt_pk_bf16_f32
  return *reinterpret_cast<unsigned int*>(&h);
}
__device__ __forceinline__ unsigned short f2bf(float f) {
  unsigned int u = __float_as_uint(f);
  u += 0x7fffu + ((u >> 16) & 1u);
  return (unsigned short)(u >> 16);
}

// ------- K1: attention. One WAVE per batch row, 4 rows/block, 1 barrier. ----
__global__ __launch_bounds__(256, 4) void k_attn(
    const int* __restrict__ sx, const float* __restrict__ dx,
    const float* __restrict__ emb, const float* __restrict__ attW,
    const float* __restrict__ attb, const float* __restrict__ attdW,
    const float* __restrict__ attdb, float* __restrict__ x)
{
  __shared__ __align__(16) float e_all[4][27 * EP];   // 29376 B (row 26 = zeros)
  __shared__ __align__(16) float sc_all[4][SCP];      // 6144 B
  __shared__ unsigned short pt[NPAD];                 // 672 B

  const int t    = threadIdx.x;
  const int lane = t & 63;
  const int wv   = t >> 6;
  const int b    = blockIdx.x * 4 + wv;               // this wave's batch row

  // pair table (f1 | f2<<8); pad rows point at zero-row 26
  for (int p = t; p < NPAD; p += 256) {
    int f1 = 26, f2 = 26;
    if (p < NPAIR) {
      int i = 0, rem = p;
      while (rem >= F - 1 - i) { rem -= F - 1 - i; ++i; }
      f1 = i; f2 = i + 1 + rem;
    }
    pt[p] = (unsigned short)(f1 | (f2 << 8));
  }

  float* e_w  = e_all[wv];
  float* sc_w = sc_all[wv];

  // wave-private gather: e[f][0..63] f32, row 26 zeroed
  for (int k = lane; k < 27 * 16; k += 64) {
    int f = k >> 4, q = k & 15;
    float4 v = {0.f, 0.f, 0.f, 0.f};
    if (f < F) {
      int row = sx[b * F + f];
      v = *(const float4*)&emb[((size_t)f * VOC + row) * D + q * 4];
    }
    *(float4*)&e_w[f * EP + q * 4] = v;
  }

  // B fragments (attW columns) + biases — global, L1-resident
  short8 bfrag[2][4];
  float bj[4], dwj[4];
  {
    const int kb = (lane >> 4) * 8;
    const int cl = lane & 15;
    #pragma unroll
    for (int kk = 0; kk < 2; ++kk)
      #pragma unroll
      for (int n = 0; n < 4; ++n)
        #pragma unroll
        for (int j = 0; j < 8; ++j) {
          int k = kk * 32 + kb + j;
          bfrag[kk][n][j] = (short)f2bf(attW[k * AD + n * 16 + cl]);
        }
    #pragma unroll
    for (int n = 0; n < 4; ++n) {
      bj[n]  = attb[n * 16 + cl];
      dwj[n] = attdW[n * 16 + cl];
    }
  }
  const float db0 = attdb[0];

  __syncthreads();   // pt table only (e_w/sc_w are wave-private)

  // ---- score GEMM: this wave does all 21 M-tiles of its row ----
  const int row16 = lane & 15;
  const int kgrp  = lane >> 4;
  for (int m = 0; m < MT; ++m) {
    const int row = m * 16 + row16;
    const unsigned short pp = pt[row];
    const float* r1 = &e_w[(pp & 0xff) * EP];
    const float* r2 = &e_w[(pp >> 8) * EP];
    FragU a0, a1;
    {
      const int k0 = kgrp * 8;
      float4 x0 = *(const float4*)&r1[k0];
      float4 x1 = *(const float4*)&r1[k0 + 4];
      float4 y0 = *(const float4*)&r2[k0];
      float4 y1 = *(const float4*)&r2[k0 + 4];
      a0.u[0] = pk2bf(x0.x * y0.x, x0.y * y0.y);
      a0.u[1] = pk2bf(x0.z * y0.z, x0.w * y0.w);
      a0.u[2] = pk2bf(x1.x * y1.x, x1.y * y1.y);
      a0.u[3] = pk2bf(x1.z * y1.z, x1.w * y1.w);
      float4 x2 = *(const float4*)&r1[32 + k0];
      float4 x3 = *(const float4*)&r1[32 + k0 + 4];
      float4 y2 = *(const float4*)&r2[32 + k0];
      float4 y3 = *(const float4*)&r2[32 + k0 + 4];
      a1.u[0] = pk2bf(x2.x * y2.x, x2.y * y2.y);
      a1.u[1] = pk2bf(x2.z * y2.z, x2.w * y2.w);
      a1.u[2] = pk2bf(x3.x * y3.x, x3.y * y3.y);
      a1.u[3] = pk2bf(x3.z * y3.z, x3.w * y3.w);
    }
    f32x4 acc[4];
    #pragma unroll
    for (int n = 0; n < 4; ++n) {
      f32x4 z = {0.f, 0.f, 0.f, 0.f};
      acc[n] = __builtin_amdgcn_mfma_f32_16x16x32_bf16(a0.s, bfrag[0][n], z, 0, 0, 0);
      acc[n] = __builtin_amdgcn_mfma_f32_16x16x32_bf16(a1.s, bfrag[1][n], acc[n], 0, 0, 0);
    }
    float v4[4];
    #pragma unroll
    for (int r = 0; r < 4; ++r) {
      float val = 0.f;
      #pragma unroll
      for (int n = 0; n < 4; ++n)
        val += fmaxf(acc[n][r] + bj[n], 0.f) * dwj[n];
      val += __shfl_xor(val, 1);
      val += __shfl_xor(val, 2);
      val += __shfl_xor(val, 4);
      val += __shfl_xor(val, 8);
      v4[r] = val + db0;
    }
    if (row16 == 0) {
      float4 o = {v4[0], v4[1], v4[2], v4[3]};
      *(float4*)&sc_w[m * 16 + kgrp * 4] = o;
    }
  }

  // ---- in-wave softmax over 325 scores (6 elems/lane) ----
  float sv[6], ev[6];
  float mx = -1e30f;
  #pragma unroll
  for (int i = 0; i < 6; ++i) {
    int idx = lane + 64 * i;
    sv[i] = (idx < NPAIR) ? sc_w[idx] : -1e30f;
    mx = fmaxf(mx, sv[i]);
  }
  #pragma unroll
  for (int off = 32; off; off >>= 1) mx = fmaxf(mx, __shfl_xor(mx, off));
  float s = 0.f;
  #pragma unroll
  for (int i = 0; i < 6; ++i) {
    int idx = lane + 64 * i;
    ev[i] = (idx < NPAIR) ? __expf(sv[i] - mx) : 0.f;
    s += ev[i];
  }
  #pragma unroll
  for (int off = 32; off; off >>= 1) s += __shfl_xor(s, off);
  const float invZ = 1.f / s;
  #pragma unroll
  for (int i = 0; i < 6; ++i) {
    int idx = lane + 64 * i;
    if (idx < NPAD) sc_w[idx] = ev[i] * invZ;      // pads get 0
  }

  // ---- PV: att_out[d] = sum_p w[p] * e1[d]*e2[d] ----
  const int g    = lane >> 3;                      // 0..7 pair-groups
  const int dblk = lane & 7;                       // d-block of 8
  float acc[8] = {0,0,0,0,0,0,0,0};
  for (int it = 0; it < NPAD / 8; ++it) {          // 42 iters
    const int p = g + 8 * it;
    const float wgt = sc_w[p];
    const unsigned short pp = pt[p];
    const float* r1 = &e_w[(pp & 0xff) * EP + dblk * 8];
    const float* r2 = &e_w[(pp >> 8) * EP + dblk * 8];
    float4 x0 = *(const float4*)r1;
    float4 x1 = *(const float4*)(r1 + 4);
    float4 y0 = *(const float4*)r2;
    float4 y1 = *(const float4*)(r2 + 4);
    acc[0] = fmaf(wgt, x0.x * y0.x, acc[0]);
    acc[1] = fmaf(wgt, x0.y * y0.y, acc[1]);
    acc[2] = fmaf(wgt, x0.z * y0.z, acc[2]);
    acc[3] = fmaf(wgt, x0.w * y0.w, acc[3]);
    acc[4] = fmaf(wgt, x1.x * y1.x, acc[4]);
    acc[5] = fmaf(wgt, x1.y * y1.y, acc[5]);
    acc[6] = fmaf(wgt, x1.z * y1.z, acc[6]);
    acc[7] = fmaf(wgt, x1.w * y1.w, acc[7]);
  }
  #pragma unroll
  for (int off = 8; off <= 32; off <<= 1)
    #pragma unroll
    for (int j = 0; j < 8; ++j)
      acc[j] += __shfl_xor(acc[j], off);
  if (g == 0) {                                    // lanes 0..7, dblk = lane
    float* xo = &x[(size_t)b * FEA + dblk * 8];
    #pragma unroll
    for (int j = 0; j < 8; ++j) xo[j] = acc[j];    // scalar: 77-stride rows unaligned
  }
  if (lane >= 8 && lane < 8 + ND) {
    x[(size_t)b * FEA + D + (lane - 8)] = dx[b * ND + (lane - 8)];
  }
}

// ---------------- K2: batchnorm stats (block per feature) ----------------
__global__ __launch_bounds__(256) void k_bnstats(
    const float* __restrict__ x, const float* __restrict__ gamma,
    const float* __restrict__ beta, float* __restrict__ scale,
    float* __restrict__ shift)
{
  const int f = blockIdx.x;
  const int t = threadIdx.x;
  const int lane = t & 63;
  const int wv = t >> 6;
  double s = 0.0, s2 = 0.0;
  for (int b = t; b < BSZ; b += 256) {
    float v = x[(size_t)b * FEA + f];
    s += v;
    s2 += (double)v * v;
  }
  #pragma unroll
  for (int off = 32; off; off >>= 1) {
    s += __shfl_xor(s, off);
    s2 += __shfl_xor(s2, off);
  }
  __shared__ double rs[4], rs2[4];
  if (lane == 0) { rs[wv] = s; rs2[wv] = s2; }
  __syncthreads();
  if (t == 0) {
    double S = 0.0, S2 = 0.0;
    #pragma unroll
    for (int i = 0; i < 4; ++i) { S += rs[i]; S2 += rs2[i]; }
    double mu = S / BSZ;
    double var = S2 / BSZ - mu * mu;
    float g = gamma[f];
    float scl = (float)((double)g / sqrt(var + (double)EPSF));
    scale[f] = scl;
    shift[f] = beta[f] - (float)mu * scl;
  }
}

// ---------------- K3: MLP (16 rows per block) ----------------
__global__ __launch_bounds__(256) void k_mlp(
    const float* __restrict__ x,
    const float* __restrict__ scale, const float* __restrict__ shift,
    const float* __restrict__ w1, const float* __restrict__ b1,
    const float* __restrict__ w2, const float* __restrict__ b2,
    const float* __restrict__ w3, const float* __restrict__ b3,
    const float* __restrict__ wf, const float* __restrict__ bf,
    float* __restrict__ out)
{
  __shared__ float xn[16][80];
  __shared__ float h1s[16][H1];
  __shared__ float h2s[16][H2];
  __shared__ float h3s[16][H3];
  const int t = threadIdx.x;
  const int b0 = blockIdx.x * 16;

  for (int k = t; k < 16 * FEA; k += 256) {
    int r = k / FEA, f = k % FEA;
    xn[r][f] = x[(size_t)(b0 + r) * FEA + f] * scale[f] + shift[f];
  }
  __syncthreads();

  {
    float acc[16];
    const float bb = b1[t];
    #pragma unroll
    for (int r = 0; r < 16; ++r) acc[r] = bb;
    for (int d = 0; d < FEA; ++d) {
      float wv = w1[d * H1 + t];
      #pragma unroll
      for (int r = 0; r < 16; ++r) acc[r] = fmaf(xn[r][d], wv, acc[r]);
    }
    #pragma unroll
    for (int r = 0; r < 16; ++r) h1s[r][t] = fmaxf(acc[r], 0.f);
  }
  __syncthreads();

  {
    const int j = t & 127;
    const int rb = (t >> 7) * 8;
    float acc[8];
    const float bb = b2[j];
    #pragma unroll
    for (int r = 0; r < 8; ++r) acc[r] = bb;
    for (int k = 0; k < H1; ++k) {
      float wv = w2[k * H2 + j];
      #pragma unroll
      for (int r = 0; r < 8; ++r) acc[r] = fmaf(h1s[rb + r][k], wv, acc[r]);
    }
    #pragma unroll
    for (int r = 0; r < 8; ++r) h2s[rb + r][j] = fmaxf(acc[r], 0.f);
  }
  __syncthreads();

  {
    const int j = t & 63;
    const int rb = (t >> 6) * 4;
    float acc[4];
    const float bb = b3[j];
    #pragma unroll
    for (int r = 0; r < 4; ++r) acc[r] = bb;
    for (int k = 0; k < H2; ++k) {
      float wv = w3[k * H3 + j];
      #pragma unroll
      for (int r = 0; r < 4; ++r) acc[r] = fmaf(h2s[rb + r][k], wv, acc[r]);
    }
    #pragma unroll
    for (int r = 0; r < 4; ++r) h3s[rb + r][j] = fmaxf(acc[r], 0.f);
  }
  __syncthreads();

  if (t < 16) {
    float acc = bf[0];
    for (int k = 0; k < H3; ++k) acc = fmaf(h3s[t][k], wf[k], acc);
    out[b0 + t] = 1.f / (1.f + expf(-acc));
  }
}

extern "C" void kernel_launch(void* const* d_in, const int* in_sizes, int n_in,
                              void* d_out, int out_size, void* d_ws, size_t ws_size,
                              hipStream_t stream) {
  const int*   sx    = (const int*)  d_in[0];
  const float* dx    = (const float*)d_in[1];
  const float* emb   = (const float*)d_in[2];
  const float* attW  = (const float*)d_in[3];
  const float* attb  = (const float*)d_in[4];
  const float* attdW = (const float*)d_in[5];
  const float* attdb = (const float*)d_in[6];
  const float* gamma = (const float*)d_in[7];
  const float* beta  = (const float*)d_in[8];
  const float* w1    = (const float*)d_in[9];
  const float* b1    = (const float*)d_in[10];
  const float* w2    = (const float*)d_in[11];
  const float* b2    = (const float*)d_in[12];
  const float* w3    = (const float*)d_in[13];
  const float* b3    = (const float*)d_in[14];
  const float* wf    = (const float*)d_in[15];
  const float* bf    = (const float*)d_in[16];
  float* out = (float*)d_out;

  float* x     = (float*)d_ws;              // B*FEA
  float* scale = x + (size_t)BSZ * FEA;     // FEA
  float* shift = scale + FEA;               // FEA

  k_attn<<<BSZ / 4, 256, 0, stream>>>(sx, dx, emb, attW, attb, attdW, attdb, x);
  k_bnstats<<<FEA, 256, 0, stream>>>(x, gamma, beta, scale, shift);
  k_mlp<<<BSZ / 16, 256, 0, stream>>>(x, scale, shift, w1, b1, w2, b2, w3, b3,
                                      wf, bf, out);
}

// Round 5
// 72.549 us; speedup vs baseline: 6.3332x; 1.3266x over previous
//
#include <hip/hip_runtime.h>
#include <hip/hip_bf16.h>
#include <math.h>

#define BSZ   4096
#define F     26
#define VOC   100000
#define D     64
#define AD    64
#define ND    13
#define FEA   77
#define NPAIR 325
#define NPAD  336    // 21 M-tiles of 16
#define MT    21
#define EP    68     // e row stride in floats
#define SCP   384
#define H1    256
#define H2    128
#define H3    64
#define EPSF  1e-5f
#define MROW  8      // k_mlp rows per block

typedef __attribute__((ext_vector_type(8))) short short8;
typedef __attribute__((ext_vector_type(4))) float f32x4;

union FragU { short8 s; unsigned int u[4]; };

__device__ __forceinline__ unsigned int pk2bf(float a, float b) {
  __hip_bfloat162 h = __float22bfloat162_rn(make_float2(a, b));  // v_cvt_pk_bf16_f32
  return *reinterpret_cast<unsigned int*>(&h);
}
__device__ __forceinline__ unsigned short f2bf(float f) {
  unsigned int u = __float_as_uint(f);
  u += 0x7fffu + ((u >> 16) & 1u);
  return (unsigned short)(u >> 16);
}
// VALU-pipe cross-lane add via DPP (no LDS pipe, no lgkmcnt latency)
template<int CTRL>
__device__ __forceinline__ float dpp_add(float x) {
  int xi = __builtin_bit_cast(int, x);
  int yi = __builtin_amdgcn_update_dpp(xi, xi, CTRL, 0xf, 0xf, false);
  return x + __builtin_bit_cast(float, yi);
}
// full 16-lane-row sum (all lanes get total): xor1, xor2, ror4, ror8
__device__ __forceinline__ float row16_sum(float x) {
  x = dpp_add<0xB1>(x);
  x = dpp_add<0x4E>(x);
  x = dpp_add<0x124>(x);
  x = dpp_add<0x128>(x);
  return x;
}

// ------- K1: attention. One WAVE per batch row, 4 rows/block, 1 barrier. ----
__global__ __launch_bounds__(256, 4) void k_attn(
    const int* __restrict__ sx, const float* __restrict__ dx,
    const float* __restrict__ emb, const float* __restrict__ attW,
    const float* __restrict__ attb, const float* __restrict__ attdW,
    const float* __restrict__ attdb, float* __restrict__ x)
{
  __shared__ __align__(16) float e_all[4][27 * EP];   // row 26 = zeros
  __shared__ __align__(16) float sc_all[4][SCP];
  __shared__ unsigned short pt[NPAD];

  const int t    = threadIdx.x;
  const int lane = t & 63;
  const int wv   = t >> 6;
  const int b    = blockIdx.x * 4 + wv;

  // pair table (f1 | f2<<8); pads -> zero-row 26
  for (int p = t; p < NPAD; p += 256) {
    int f1 = 26, f2 = 26;
    if (p < NPAIR) {
      int i = 0, rem = p;
      while (rem >= F - 1 - i) { rem -= F - 1 - i; ++i; }
      f1 = i; f2 = i + 1 + rem;
    }
    pt[p] = (unsigned short)(f1 | (f2 << 8));
  }

  float* e_w  = e_all[wv];
  float* sc_w = sc_all[wv];

  // gather: all index loads, then all emb loads, then all LDS stores (ILP)
  {
    int rowsv[7]; float4 vv[7];
    #pragma unroll
    for (int i = 0; i < 7; ++i) {
      int k = lane + 64 * i, f = k >> 4;
      rowsv[i] = (f < F) ? sx[b * F + f] : 0;
    }
    #pragma unroll
    for (int i = 0; i < 7; ++i) {
      int k = lane + 64 * i, f = k >> 4, q = k & 15;
      float4 v = {0.f, 0.f, 0.f, 0.f};
      if (f < F) v = *(const float4*)&emb[((size_t)f * VOC + rowsv[i]) * D + q * 4];
      vv[i] = v;
    }
    #pragma unroll
    for (int i = 0; i < 7; ++i) {
      int k = lane + 64 * i, f = k >> 4, q = k & 15;
      if (f < 27) *(float4*)&e_w[f * EP + q * 4] = vv[i];
    }
  }

  // B fragments (attW columns) + biases — global, L1/L2-resident
  short8 bfrag[2][4];
  float bj[4], dwj[4];
  {
    const int kb = (lane >> 4) * 8;
    const int cl = lane & 15;
    #pragma unroll
    for (int kk = 0; kk < 2; ++kk)
      #pragma unroll
      for (int n = 0; n < 4; ++n)
        #pragma unroll
        for (int j = 0; j < 8; ++j) {
          int k = kk * 32 + kb + j;
          bfrag[kk][n][j] = (short)f2bf(attW[k * AD + n * 16 + cl]);
        }
    #pragma unroll
    for (int n = 0; n < 4; ++n) {
      bj[n]  = attb[n * 16 + cl];
      dwj[n] = attdW[n * 16 + cl];
    }
  }
  const float db0 = attdb[0];

  __syncthreads();   // pt table only (e_w/sc_w are wave-private)

  // ---- score GEMM: 21 M-tiles ----
  const int row16 = lane & 15;
  const int kgrp  = lane >> 4;
  for (int m = 0; m < MT; ++m) {
    const int row = m * 16 + row16;
    const unsigned short pp = pt[row];
    const float* r1 = &e_w[(pp & 0xff) * EP];
    const float* r2 = &e_w[(pp >> 8) * EP];
    FragU a0, a1;
    {
      const int k0 = kgrp * 8;
      float4 x0 = *(const float4*)&r1[k0];
      float4 x1 = *(const float4*)&r1[k0 + 4];
      float4 y0 = *(const float4*)&r2[k0];
      float4 y1 = *(const float4*)&r2[k0 + 4];
      a0.u[0] = pk2bf(x0.x * y0.x, x0.y * y0.y);
      a0.u[1] = pk2bf(x0.z * y0.z, x0.w * y0.w);
      a0.u[2] = pk2bf(x1.x * y1.x, x1.y * y1.y);
      a0.u[3] = pk2bf(x1.z * y1.z, x1.w * y1.w);
      float4 x2 = *(const float4*)&r1[32 + k0];
      float4 x3 = *(const float4*)&r1[32 + k0 + 4];
      float4 y2 = *(const float4*)&r2[32 + k0];
      float4 y3 = *(const float4*)&r2[32 + k0 + 4];
      a1.u[0] = pk2bf(x2.x * y2.x, x2.y * y2.y);
      a1.u[1] = pk2bf(x2.z * y2.z, x2.w * y2.w);
      a1.u[2] = pk2bf(x3.x * y3.x, x3.y * y3.y);
      a1.u[3] = pk2bf(x3.z * y3.z, x3.w * y3.w);
    }
    f32x4 acc[4];
    #pragma unroll
    for (int n = 0; n < 4; ++n) {
      f32x4 z = {0.f, 0.f, 0.f, 0.f};
      acc[n] = __builtin_amdgcn_mfma_f32_16x16x32_bf16(a0.s, bfrag[0][n], z, 0, 0, 0);
      acc[n] = __builtin_amdgcn_mfma_f32_16x16x32_bf16(a1.s, bfrag[1][n], acc[n], 0, 0, 0);
    }
    float v4[4];
    #pragma unroll
    for (int r = 0; r < 4; ++r) {
      float val = 0.f;
      #pragma unroll
      for (int n = 0; n < 4; ++n)
        val += fmaxf(acc[n][r] + bj[n], 0.f) * dwj[n];
      v4[r] = row16_sum(val) + db0;   // VALU DPP reduce over 16 lanes
    }
    if (row16 == 0) {
      float4 o = {v4[0], v4[1], v4[2], v4[3]};
      *(float4*)&sc_w[m * 16 + kgrp * 4] = o;
    }
  }

  // ---- in-wave softmax over 325 scores ----
  float sv[6], ev[6];
  float mx = -1e30f;
  #pragma unroll
  for (int i = 0; i < 6; ++i) {
    int idx = lane + 64 * i;
    sv[i] = (idx < NPAIR) ? sc_w[idx] : -1e30f;
    mx = fmaxf(mx, sv[i]);
  }
  #pragma unroll
  for (int off = 32; off; off >>= 1) mx = fmaxf(mx, __shfl_xor(mx, off));
  float s = 0.f;
  #pragma unroll
  for (int i = 0; i < 6; ++i) {
    int idx = lane + 64 * i;
    ev[i] = (idx < NPAIR) ? __expf(sv[i] - mx) : 0.f;
    s += ev[i];
  }
  #pragma unroll
  for (int off = 32; off; off >>= 1) s += __shfl_xor(s, off);
  const float invZ = 1.f / s;
  #pragma unroll
  for (int i = 0; i < 6; ++i) {
    int idx = lane + 64 * i;
    if (idx < NPAD) sc_w[idx] = ev[i] * invZ;      // pads get 0
  }

  // ---- PV: att_out[d] = sum_p w[p] * e1[d]*e2[d] ----
  // dblk = lane>>3 so the 8-way pair reduce is within 8 consecutive lanes (DPP)
  const int dblk = lane >> 3;                      // d-block of 8
  const int g    = lane & 7;                       // pair group
  float acc[8] = {0,0,0,0,0,0,0,0};
  for (int it = 0; it < NPAD / 8; ++it) {          // 42 iters
    const int p = g + 8 * it;
    const float wgt = sc_w[p];
    const unsigned short pp = pt[p];
    const float* r1 = &e_w[(pp & 0xff) * EP + dblk * 8];
    const float* r2 = &e_w[(pp >> 8) * EP + dblk * 8];
    float4 x0 = *(const float4*)r1;
    float4 x1 = *(const float4*)(r1 + 4);
    float4 y0 = *(const float4*)r2;
    float4 y1 = *(const float4*)(r2 + 4);
    acc[0] = fmaf(wgt, x0.x * y0.x, acc[0]);
    acc[1] = fmaf(wgt, x0.y * y0.y, acc[1]);
    acc[2] = fmaf(wgt, x0.z * y0.z, acc[2]);
    acc[3] = fmaf(wgt, x0.w * y0.w, acc[3]);
    acc[4] = fmaf(wgt, x1.x * y1.x, acc[4]);
    acc[5] = fmaf(wgt, x1.y * y1.y, acc[5]);
    acc[6] = fmaf(wgt, x1.z * y1.z, acc[6]);
    acc[7] = fmaf(wgt, x1.w * y1.w, acc[7]);
  }
  #pragma unroll
  for (int j = 0; j < 8; ++j) {                    // reduce over g (lanes i, i^1, i^2, i+4)
    acc[j] = dpp_add<0xB1>(acc[j]);
    acc[j] = dpp_add<0x4E>(acc[j]);
    acc[j] = dpp_add<0x124>(acc[j]);               // row_ror:4 — valid at g==0
  }
  if (g == 0) {                                    // lanes 0,8,..,56
    float* xo = &x[(size_t)b * FEA + dblk * 8];
    #pragma unroll
    for (int j = 0; j < 8; ++j) xo[j] = acc[j];
  }
  if (lane >= 8 && lane < 8 + ND) {
    x[(size_t)b * FEA + D + (lane - 8)] = dx[b * ND + (lane - 8)];
  }
}

// ---------------- K2: batchnorm stats (block per feature) ----------------
__global__ __launch_bounds__(256) void k_bnstats(
    const float* __restrict__ x, const float* __restrict__ gamma,
    const float* __restrict__ beta, float* __restrict__ scale,
    float* __restrict__ shift)
{
  const int f = blockIdx.x;
  const int t = threadIdx.x;
  const int lane = t & 63;
  const int wv = t >> 6;
  double s = 0.0, s2 = 0.0;
  for (int b = t; b < BSZ; b += 256) {
    float v = x[(size_t)b * FEA + f];
    s += v;
    s2 += (double)v * v;
  }
  #pragma unroll
  for (int off = 32; off; off >>= 1) {
    s += __shfl_xor(s, off);
    s2 += __shfl_xor(s2, off);
  }
  __shared__ double rs[4], rs2[4];
  if (lane == 0) { rs[wv] = s; rs2[wv] = s2; }
  __syncthreads();
  if (t == 0) {
    double S = 0.0, S2 = 0.0;
    #pragma unroll
    for (int i = 0; i < 4; ++i) { S += rs[i]; S2 += rs2[i]; }
    double mu = S / BSZ;
    double var = S2 / BSZ - mu * mu;
    float g = gamma[f];
    float scl = (float)((double)g / sqrt(var + (double)EPSF));
    scale[f] = scl;
    shift[f] = beta[f] - (float)mu * scl;
  }
}

// ---------------- K3: MLP (8 rows per block, 512 blocks) ----------------
__global__ __launch_bounds__(256) void k_mlp(
    const float* __restrict__ x,
    const float* __restrict__ scale, const float* __restrict__ shift,
    const float* __restrict__ w1, const float* __restrict__ b1,
    const float* __restrict__ w2, const float* __restrict__ b2,
    const float* __restrict__ w3, const float* __restrict__ b3,
    const float* __restrict__ wf, const float* __restrict__ bf,
    float* __restrict__ out)
{
  __shared__ float xn[MROW][80];
  __shared__ float h1s[MROW][H1];
  __shared__ float h2s[MROW][H2];
  __shared__ float h3s[MROW][H3];
  const int t = threadIdx.x;
  const int b0 = blockIdx.x * MROW;

  for (int k = t; k < MROW * FEA; k += 256) {
    int r = k / FEA, f = k % FEA;
    xn[r][f] = x[(size_t)(b0 + r) * FEA + f] * scale[f] + shift[f];
  }
  __syncthreads();

  {
    float acc[MROW];
    const float bb = b1[t];
    #pragma unroll
    for (int r = 0; r < MROW; ++r) acc[r] = bb;
    for (int d = 0; d < FEA; ++d) {
      float wv = w1[d * H1 + t];
      #pragma unroll
      for (int r = 0; r < MROW; ++r) acc[r] = fmaf(xn[r][d], wv, acc[r]);
    }
    #pragma unroll
    for (int r = 0; r < MROW; ++r) h1s[r][t] = fmaxf(acc[r], 0.f);
  }
  __syncthreads();

  {
    const int j = t & 127;
    const int rb = (t >> 7) * 4;
    float acc[4];
    const float bb = b2[j];
    #pragma unroll
    for (int r = 0; r < 4; ++r) acc[r] = bb;
    for (int k = 0; k < H1; ++k) {
      float wv = w2[k * H2 + j];
      #pragma unroll
      for (int r = 0; r < 4; ++r) acc[r] = fmaf(h1s[rb + r][k], wv, acc[r]);
    }
    #pragma unroll
    for (int r = 0; r < 4; ++r) h2s[rb + r][j] = fmaxf(acc[r], 0.f);
  }
  __syncthreads();

  {
    const int j = t & 63;
    const int rb = (t >> 6) * 2;
    float acc[2];
    const float bb = b3[j];
    #pragma unroll
    for (int r = 0; r < 2; ++r) acc[r] = bb;
    for (int k = 0; k < H2; ++k) {
      float wv = w3[k * H3 + j];
      #pragma unroll
      for (int r = 0; r < 2; ++r) acc[r] = fmaf(h2s[rb + r][k], wv, acc[r]);
    }
    #pragma unroll
    for (int r = 0; r < 2; ++r) h3s[rb + r][j] = fmaxf(acc[r], 0.f);
  }
  __syncthreads();

  if (t < MROW) {
    float acc = bf[0];
    for (int k = 0; k < H3; ++k) acc = fmaf(h3s[t][k], wf[k], acc);
    out[b0 + t] = 1.f / (1.f + __expf(-acc));
  }
}

extern "C" void kernel_launch(void* const* d_in, const int* in_sizes, int n_in,
                              void* d_out, int out_size, void* d_ws, size_t ws_size,
                              hipStream_t stream) {
  const int*   sx    = (const int*)  d_in[0];
  const float* dx    = (const float*)d_in[1];
  const float* emb   = (const float*)d_in[2];
  const float* attW  = (const float*)d_in[3];
  const float* attb  = (const float*)d_in[4];
  const float* attdW = (const float*)d_in[5];
  const float* attdb = (const float*)d_in[6];
  const float* gamma = (const float*)d_in[7];
  const float* beta  = (const float*)d_in[8];
  const float* w1    = (const float*)d_in[9];
  const float* b1    = (const float*)d_in[10];
  const float* w2    = (const float*)d_in[11];
  const float* b2    = (const float*)d_in[12];
  const float* w3    = (const float*)d_in[13];
  const float* b3    = (const float*)d_in[14];
  const float* wf    = (const float*)d_in[15];
  const float* bf    = (const float*)d_in[16];
  float* out = (float*)d_out;

  float* x     = (float*)d_ws;              // B*FEA
  float* scale = x + (size_t)BSZ * FEA;     // FEA
  float* shift = scale + FEA;               // FEA

  k_attn<<<BSZ / 4, 256, 0, stream>>>(sx, dx, emb, attW, attb, attdW, attdb, x);
  k_bnstats<<<FEA, 256, 0, stream>>>(x, gamma, beta, scale, shift);
  k_mlp<<<BSZ / MROW, 256, 0, stream>>>(x, scale, shift, w1, b1, w2, b2, w3, b3,
                                        wf, bf, out);
}